// Round 4
// baseline (238.683 us; speedup 1.0000x reference)
//
#include <hip/hip_runtime.h>
#include <hip/hip_bf16.h>
#include <hip/hip_cooperative_groups.h>

namespace cg = cooperative_groups;

typedef unsigned short u16;
typedef __attribute__((ext_vector_type(4))) int   int4v;
typedef __attribute__((ext_vector_type(4))) unsigned int uint4v;
typedef __attribute__((ext_vector_type(4))) unsigned short ushort4v;
typedef __attribute__((ext_vector_type(4))) float floatx4;
typedef __attribute__((ext_vector_type(8))) short bf16x8;

#define LRELU_NS 0.01f
#define SK 264   // LDS k-stride (bf16): 256 + 8 pad, 16B-aligned rows

__device__ __forceinline__ float bitsToF(unsigned int b) {
    union { unsigned int u; float f; } v; v.u = b << 16; return v.f;
}
__device__ __forceinline__ float bfLo(unsigned int d) {
    union { unsigned int u; float f; } v; v.u = d << 16; return v.f;
}
__device__ __forceinline__ float bfHi(unsigned int d) {
    union { unsigned int u; float f; } v; v.u = d & 0xffff0000u; return v.f;
}
__device__ __forceinline__ u16 f2bf(float f) {
    __hip_bfloat16 h = __float2bfloat16(f);
    return *reinterpret_cast<u16*>(&h);
}
__device__ __forceinline__ float lrelu(float v) {
    return fmaxf(v, LRELU_NS * v);
}
__device__ __forceinline__ u16 ldW(const void* p, int i, int isF32) {
    return isF32 ? f2bf(((const float*)p)[i]) : ((const u16*)p)[i];
}
__device__ __forceinline__ float ldF(const void* p, int i, int isF32) {
    return isF32 ? ((const float*)p)[i]
                 : bitsToF((unsigned int)((const u16*)p)[i]);
}

// dtype probe (verified) — all threads of the block must call.
__device__ __forceinline__ int computeIsF32(const u16* y, int* cnt, int t) {
    if (t == 0) *cnt = 0;
    __syncthreads();
    if (t < 256) {
        u16 v = y[2 * t];
        int e = (v >> 7) & 0xFF;
        if (v == 0 || (e >= 96 && e < 160)) atomicAdd(cnt, 1);
    }
    __syncthreads();
    return (*cnt < 192) ? 1 : 0;
}

// ---------------------------------------------------------------------------
// MEGA: one cooperative persistent kernel (phases: pack | L1+headsL2+P | pairf)
// LDS union max 67.6 KB -> 2 blocks/CU. Math bodies verbatim from the
// harness-verified kernels; persistent loops are grid-size-agnostic.
// ---------------------------------------------------------------------------
union SharedU {
    u16 tile[64][65];                                     // phase0
    struct { u16 Xs[64 * SK]; u16 Hb[64 * SK]; } p1;      // phase1
    struct { u16 Pq[4][16 * SK]; u16 WsB[16 * 264]; } p2; // phase2
};

__global__ __launch_bounds__(512) void mega_kernel(
    const void* __restrict__ yhat,
    const void* __restrict__ Ws1, const void* __restrict__ Wc1,
    const void* __restrict__ Wb1, const void* __restrict__ Ws2,
    const void* __restrict__ Wc2,
    const void* __restrict__ bs1, const void* __restrict__ bc1,
    const void* __restrict__ bb1, const void* __restrict__ bs2,
    const void* __restrict__ bc2, const void* __restrict__ bb2,
    const void* __restrict__ Wb2,
    u16* __restrict__ WallT, u16* __restrict__ W2T, float* __restrict__ biasF,
    u16* __restrict__ P1g, u16* __restrict__ P2g, void* __restrict__ outv)
{
    __shared__ SharedU sh;
    __shared__ int fcnt;
    const int t = threadIdx.x;
    const int isF32 = computeIsF32((const u16*)yhat, &fcnt, t);
    cg::grid_group grid = cg::this_grid();

    const int w = t >> 6, l = t & 63;
    const int ml = l & 15, kq = l >> 4, r0 = kq * 4;

    // ---------------- phase 0: pack (98 jobs) ----------------
    for (int job = blockIdx.x; job < 98; job += gridDim.x) {
        if (job < 64) {
            const int c0 = (job & 15) * 64;
            const int k0 = (job >> 4) * 64;
            const void* src; int coff; int roff = 0;
            if (c0 < 256)      { src = Ws1; coff = c0; }
            else if (c0 < 512) { src = Wc1; coff = c0 - 256; }
            else if (c0 < 768) { src = Wb1; coff = c0 - 512; }
            else               { src = Wb1; coff = c0 - 768; roff = 256; }
            const int cc = t & 63, kk0 = t >> 6;
            #pragma unroll
            for (int i = 0; i < 8; ++i) {
                int kk = kk0 + i * 8;
                sh.tile[kk][cc] = ldW(src, (k0 + kk + roff) * 256 + coff + cc, isF32);
            }
            __syncthreads();
            const int kk2 = t & 63, cc0 = t >> 6;
            #pragma unroll
            for (int i = 0; i < 8; ++i) {
                int cc2 = cc0 + i * 8;
                WallT[(c0 + cc2) * 256 + (k0 + kk2)] = sh.tile[kk2][cc2];
            }
            __syncthreads();                     // tile reuse guard
        } else if (job < 96) {
            int e2 = (job - 64) * 512 + t;       // < 16384
            int c = e2 >> 8, k = e2 & 255;
            u16 v = 0;
            if (c < 40)                 v = ldW(Ws2, k * 40 + c, isF32);
            else if (c >= 48 && c < 53) v = ldW(Wc2, k * 5 + (c - 48), isF32);
            W2T[c * 256 + k] = v;
        } else {
            int idx = (job - 96) * 512 + t;      // < 1024
            float v = 0.f;
            if (idx < 256)       v = ldF(bs1, idx, isF32);
            else if (idx < 512)  v = ldF(bc1, idx - 256, isF32);
            else if (idx < 768)  v = ldF(bb1, idx - 512, isF32);
            else if (idx < 808)  v = ldF(bs2, idx - 768, isF32);
            else if (idx < 813)  v = ldF(bc2, idx - 808, isF32);
            else if (idx >= 816 && idx < 821) v = ldF(bb2, idx - 816, isF32);
            biasF[idx] = v;
        }
    }
    grid.sync();

    // ---------------- phase 1: 480 jobs (160 bm x {sym, chg, P}) ----------------
    for (int job = blockIdx.x; job < 480; job += gridDim.x) {
        const int bm0 = (job % 160) * 64;
        const int y = job / 160;                 // 0,1,2
        if (isF32) {
            const floatx4* __restrict__ src = (const floatx4*)((const float*)yhat + bm0 * 256);
            #pragma unroll
            for (int s = 0; s < 8; ++s) {
                int cid = t + s * 512;
                int row = cid >> 6, ch = cid & 63;
                floatx4 f = src[cid];
                ushort4v u;
                u[0] = f2bf(f[0]); u[1] = f2bf(f[1]); u[2] = f2bf(f[2]); u[3] = f2bf(f[3]);
                *(ushort4v*)&sh.p1.Xs[row * SK + ch * 4] = u;
            }
        } else {
            const int4v* __restrict__ src = (const int4v*)((const u16*)yhat + bm0 * 256);
            #pragma unroll
            for (int s = 0; s < 4; ++s) {
                int cid = t + s * 512;
                int row = cid >> 5, ch = cid & 31;
                *(int4v*)&sh.p1.Xs[row * SK + ch * 8] = src[cid];
            }
        }
        __syncthreads();

        if (y < 2) {
            #pragma unroll
            for (int n = 0; n < 2; ++n) {
                const int ct = w + 8 * n;
                floatx4 acc[4] = {};
                #pragma unroll
                for (int ks = 0; ks < 8; ++ks) {
                    const int k0 = ks * 32 + kq * 8;
                    bf16x8 bf = *(const bf16x8*)&WallT[(y * 256 + ct * 16 + ml) * 256 + k0];
                    #pragma unroll
                    for (int mt = 0; mt < 4; ++mt) {
                        bf16x8 a = *(const bf16x8*)&sh.p1.Xs[(mt * 16 + ml) * SK + k0];
                        acc[mt] = __builtin_amdgcn_mfma_f32_16x16x32_bf16(a, bf, acc[mt], 0, 0, 0);
                    }
                }
                const int col = ct * 16 + ml;
                const float bias = biasF[y * 256 + col];
                #pragma unroll
                for (int mt = 0; mt < 4; ++mt)
                    #pragma unroll
                    for (int r = 0; r < 4; ++r)
                        sh.p1.Hb[(mt * 16 + r0 + r) * SK + col] = f2bf(lrelu(acc[mt][r] + bias));
            }
            __syncthreads();   // Hb complete
            if (w < 4) {
                const int nct = (y == 0) ? 3 : 1;
                const int c0  = (y == 0) ? 0 : 48;
                floatx4 acc2[3] = {};
                #pragma unroll
                for (int ks = 0; ks < 8; ++ks) {
                    const int k0 = ks * 32 + kq * 8;
                    bf16x8 a = *(const bf16x8*)&sh.p1.Hb[(w * 16 + ml) * SK + k0];
                    #pragma unroll
                    for (int j = 0; j < 3; ++j) {
                        if (j < nct) {
                            bf16x8 bf = *(const bf16x8*)&W2T[(c0 + j * 16 + ml) * 256 + k0];
                            acc2[j] = __builtin_amdgcn_mfma_f32_16x16x32_bf16(a, bf, acc2[j], 0, 0, 0);
                        }
                    }
                }
                #pragma unroll
                for (int j = 0; j < 3; ++j) {
                    if (j < nct) {
                        const int col = j * 16 + ml;
                        const int lim = (y == 0) ? 40 : 5;
                        if (col < lim) {
                            const float bias = biasF[(y == 0 ? 768 : 808) + col];
                            #pragma unroll
                            for (int r = 0; r < 4; ++r) {
                                const int row = bm0 + w * 16 + r0 + r;
                                const int o = (y == 0) ? row * 40 + col
                                                       : 409600 + row * 5 + col;
                                const float v = acc2[j][r] + bias;
                                if (isF32) ((float*)outv)[o] = v;
                                else ((__hip_bfloat16*)outv)[o] = __float2bfloat16(v);
                            }
                        }
                    }
                }
            }
        } else {
            #pragma unroll
            for (int s = 0; s < 2; ++s) {
                u16* __restrict__ dst = s ? P2g : P1g;
                #pragma unroll
                for (int n = 0; n < 2; ++n) {
                    const int ct = w + 8 * n;
                    const int col = ct * 16 + ml;
                    floatx4 acc[4] = {};
                    #pragma unroll
                    for (int ks = 0; ks < 8; ++ks) {
                        const int k0 = ks * 32 + kq * 8;
                        bf16x8 bf = *(const bf16x8*)&WallT[(512 + s * 256 + col) * 256 + k0];
                        #pragma unroll
                        for (int mt = 0; mt < 4; ++mt) {
                            bf16x8 a = *(const bf16x8*)&sh.p1.Xs[(mt * 16 + ml) * SK + k0];
                            acc[mt] = __builtin_amdgcn_mfma_f32_16x16x32_bf16(a, bf, acc[mt], 0, 0, 0);
                        }
                    }
                    const float bias = s ? 0.f : biasF[512 + col];   // bb1 on P1 only
                    #pragma unroll
                    for (int mt = 0; mt < 4; ++mt)
                        #pragma unroll
                        for (int r = 0; r < 4; ++r)
                            dst[(bm0 + mt * 16 + r0 + r) * 256 + col] = f2bf(acc[mt][r] + bias);
                }
            }
        }
        __syncthreads();   // LDS reuse guard
    }
    grid.sync();

    // ---------------- phase 2: pairf (1536 jobs) ----------------
    for (int job = blockIdx.x; job < 1536; job += gridDim.x) {
        const int mol = job / 6;
        const int yb = job - mol * 6;
        const int it = (yb < 3) ? 0 : (yb < 5) ? 1 : 2;
        const int jt = (yb < 3) ? yb : (yb < 5) ? (yb - 2) : 2;

        #pragma unroll
        for (int s = 0; s < 4; ++s) {
            const int cid = t + s * 512;
            const int buf = cid >> 9, r = (cid >> 5) & 15, ch = cid & 31;
            const int tile = (buf < 2) ? it : jt;
            const u16* __restrict__ src = (buf & 1) ? P2g : P1g;
            const int arow = tile * 16 + r;
            int4v v = {0, 0, 0, 0};
            if (arow < 40) v = *(const int4v*)&src[(mol * 40 + arow) * 256 + ch * 8];
            *(int4v*)&sh.p2.Pq[buf][r * SK + ch * 8] = v;
        }
        #pragma unroll
        for (int s = 0; s < 8; ++s) {
            const int e2 = t + s * 512;
            const int c = e2 >> 8, k = e2 & 255;
            sh.p2.WsB[c * 264 + k] = (c < 5) ? ldW(Wb2, k * 5 + c, isF32) : (u16)0;
        }
        __syncthreads();

        bf16x8 wf[8];
        #pragma unroll
        for (int ks = 0; ks < 8; ++ks)
            wf[ks] = *(const bf16x8*)&sh.p2.WsB[ml * 264 + ks * 32 + kq * 8];
        const float b2x2 = 2.f * biasF[816 + ml];

        const int i0 = it * 16 + w;
        const int i1 = i0 + 8;
        const bool do1 = (it != 2);
        floatx4 acc0 = {}, acc1 = {};
        #pragma unroll
        for (int ks = 0; ks < 8; ++ks) {
            const int k0 = ks * 32 + kq * 8;
            const uint4v b1 = *(const uint4v*)&sh.p2.Pq[2][ml * SK + k0];
            const uint4v b2 = *(const uint4v*)&sh.p2.Pq[3][ml * SK + k0];
            {
                const uint4v a1 = *(const uint4v*)&sh.p2.Pq[0][w * SK + k0];
                const uint4v a2 = *(const uint4v*)&sh.p2.Pq[1][w * SK + k0];
                bf16x8 af;
                #pragma unroll
                for (int d = 0; d < 4; ++d) {
                    const float sLo = lrelu(bfLo(a1[d]) + bfLo(b2[d]))
                                    + lrelu(bfLo(b1[d]) + bfLo(a2[d]));
                    const float sHi = lrelu(bfHi(a1[d]) + bfHi(b2[d]))
                                    + lrelu(bfHi(b1[d]) + bfHi(a2[d]));
                    af[2 * d]     = (short)f2bf(sLo);
                    af[2 * d + 1] = (short)f2bf(sHi);
                }
                acc0 = __builtin_amdgcn_mfma_f32_16x16x32_bf16(af, wf[ks], acc0, 0, 0, 0);
            }
            if (do1) {
                const uint4v a1 = *(const uint4v*)&sh.p2.Pq[0][(w + 8) * SK + k0];
                const uint4v a2 = *(const uint4v*)&sh.p2.Pq[1][(w + 8) * SK + k0];
                bf16x8 af;
                #pragma unroll
                for (int d = 0; d < 4; ++d) {
                    const float sLo = lrelu(bfLo(a1[d]) + bfLo(b2[d]))
                                    + lrelu(bfLo(b1[d]) + bfLo(a2[d]));
                    const float sHi = lrelu(bfHi(a1[d]) + bfHi(b2[d]))
                                    + lrelu(bfHi(b1[d]) + bfHi(a2[d]));
                    af[2 * d]     = (short)f2bf(sLo);
                    af[2 * d + 1] = (short)f2bf(sHi);
                }
                acc1 = __builtin_amdgcn_mfma_f32_16x16x32_bf16(af, wf[ks], acc1, 0, 0, 0);
            }
        }

        if (ml < 5) {
            #pragma unroll
            for (int r = 0; r < 4; ++r) {
                const int j = jt * 16 + r0 + r;
                if (j < 40 && (it != jt || j >= i0)) {
                    const float v = acc0[r] + b2x2;
                    const int o1 = 460800 + (mol * 1600 + i0 * 40 + j) * 5 + ml;
                    if (isF32) ((float*)outv)[o1] = v;
                    else ((__hip_bfloat16*)outv)[o1] = __float2bfloat16(v);
                    if (it != jt || j > i0) {
                        const int o2 = 460800 + (mol * 1600 + j * 40 + i0) * 5 + ml;
                        if (isF32) ((float*)outv)[o2] = v;
                        else ((__hip_bfloat16*)outv)[o2] = __float2bfloat16(v);
                    }
                }
            }
            if (do1) {
                #pragma unroll
                for (int r = 0; r < 4; ++r) {
                    const int j = jt * 16 + r0 + r;
                    if (j < 40 && (it != jt || j >= i1)) {
                        const float v = acc1[r] + b2x2;
                        const int o1 = 460800 + (mol * 1600 + i1 * 40 + j) * 5 + ml;
                        if (isF32) ((float*)outv)[o1] = v;
                        else ((__hip_bfloat16*)outv)[o1] = __float2bfloat16(v);
                        if (it != jt || j > i1) {
                            const int o2 = 460800 + (mol * 1600 + j * 40 + i1) * 5 + ml;
                            if (isF32) ((float*)outv)[o2] = v;
                            else ((__hip_bfloat16*)outv)[o2] = __float2bfloat16(v);
                        }
                    }
                }
            }
        }
        __syncthreads();   // LDS reuse guard
    }
}

// ---------------------------------------------------------------------------
// FALLBACK kernels (verified R3 pipeline).
// ---------------------------------------------------------------------------
__global__ __launch_bounds__(256) void pack_kernel(
    const void* __restrict__ yhat,
    const void* __restrict__ Ws1, const void* __restrict__ Wc1,
    const void* __restrict__ Wb1, const void* __restrict__ Ws2,
    const void* __restrict__ Wc2,
    const void* __restrict__ bs1, const void* __restrict__ bc1,
    const void* __restrict__ bb1, const void* __restrict__ bs2,
    const void* __restrict__ bc2, const void* __restrict__ bb2,
    u16* __restrict__ WallT, u16* __restrict__ W2T, float* __restrict__ biasF)
{
    __shared__ int fcnt;
    const int bid = blockIdx.x, t = threadIdx.x;
    const int isF32 = computeIsF32((const u16*)yhat, &fcnt, t);
    if (bid < 64) {
        __shared__ u16 tile[64][65];
        const int c0 = (bid & 15) * 64;
        const int k0 = (bid >> 4) * 64;
        const void* src; int coff; int roff = 0;
        if (c0 < 256)      { src = Ws1; coff = c0; }
        else if (c0 < 512) { src = Wc1; coff = c0 - 256; }
        else if (c0 < 768) { src = Wb1; coff = c0 - 512; }
        else               { src = Wb1; coff = c0 - 768; roff = 256; }
        const int cc = t & 63, kk0 = t >> 6;
        #pragma unroll
        for (int i = 0; i < 16; ++i) {
            int kk = kk0 + i * 4;
            tile[kk][cc] = ldW(src, (k0 + kk + roff) * 256 + coff + cc, isF32);
        }
        __syncthreads();
        const int kk2 = t & 63, cc0 = t >> 6;
        #pragma unroll
        for (int i = 0; i < 16; ++i) {
            int cc2 = cc0 + i * 4;
            WallT[(c0 + cc2) * 256 + (k0 + kk2)] = tile[kk2][cc2];
        }
    } else if (bid < 128) {
        int e2 = (bid - 64) * 256 + t;
        int c = e2 >> 8, k = e2 & 255;
        u16 v = 0;
        if (c < 40)                 v = ldW(Ws2, k * 40 + c, isF32);
        else if (c >= 48 && c < 53) v = ldW(Wc2, k * 5 + (c - 48), isF32);
        W2T[c * 256 + k] = v;
    } else {
        int idx = (bid - 128) * 256 + t;
        float v = 0.f;
        if (idx < 256)       v = ldF(bs1, idx, isF32);
        else if (idx < 512)  v = ldF(bc1, idx - 256, isF32);
        else if (idx < 768)  v = ldF(bb1, idx - 512, isF32);
        else if (idx < 808)  v = ldF(bs2, idx - 768, isF32);
        else if (idx < 813)  v = ldF(bc2, idx - 808, isF32);
        else if (idx >= 816 && idx < 821) v = ldF(bb2, idx - 816, isF32);
        biasF[idx] = v;
    }
}

__global__ __launch_bounds__(256) void heads_kernel(
    const void* __restrict__ Xv, const u16* __restrict__ WallT,
    const u16* __restrict__ W2T, const float* __restrict__ biasF,
    void* __restrict__ outv)
{
    __shared__ u16 Xs[64 * SK];
    __shared__ u16 Hb[64 * SK];
    __shared__ int fcnt;
    const int t = threadIdx.x;
    const int bm0 = blockIdx.x * 64;
    const int head = blockIdx.y;
    const int isF32 = computeIsF32((const u16*)Xv, &fcnt, t);

    if (isF32) {
        const floatx4* __restrict__ src = (const floatx4*)((const float*)Xv + bm0 * 256);
        #pragma unroll
        for (int it = 0; it < 16; ++it) {
            int cid = t + it * 256;
            int row = cid >> 6, ch = cid & 63;
            floatx4 f = src[cid];
            ushort4v u;
            u[0] = f2bf(f[0]); u[1] = f2bf(f[1]); u[2] = f2bf(f[2]); u[3] = f2bf(f[3]);
            *(ushort4v*)&Xs[row * SK + ch * 4] = u;
        }
    } else {
        const int4v* __restrict__ src = (const int4v*)((const u16*)Xv + bm0 * 256);
        #pragma unroll
        for (int it = 0; it < 8; ++it) {
            int cid = t + it * 256;
            int row = cid >> 5, ch = cid & 31;
            *(int4v*)&Xs[row * SK + ch * 8] = src[cid];
        }
    }
    __syncthreads();

    const int w = t >> 6, l = t & 63;
    const int ml = l & 15, kq = l >> 4, r0 = kq * 4;

    for (int n = 0; n < 4; ++n) {
        const int ct = w + 4 * n;
        floatx4 acc[4] = {};
        #pragma unroll
        for (int ks = 0; ks < 8; ++ks) {
            const int k0 = ks * 32 + kq * 8;
            bf16x8 bf = *(const bf16x8*)&WallT[(head * 256 + ct * 16 + ml) * 256 + k0];
            #pragma unroll
            for (int mt = 0; mt < 4; ++mt) {
                bf16x8 a = *(const bf16x8*)&Xs[(mt * 16 + ml) * SK + k0];
                acc[mt] = __builtin_amdgcn_mfma_f32_16x16x32_bf16(a, bf, acc[mt], 0, 0, 0);
            }
        }
        const int col = ct * 16 + ml;
        const float bias = biasF[head * 256 + col];
        #pragma unroll
        for (int mt = 0; mt < 4; ++mt)
            #pragma unroll
            for (int r = 0; r < 4; ++r)
                Hb[(mt * 16 + r0 + r) * SK + col] = f2bf(lrelu(acc[mt][r] + bias));
    }
    __syncthreads();

    const int nct = (head == 0) ? 3 : 1;
    const int c0  = (head == 0) ? 0 : 48;
    floatx4 acc2[3] = {};
    #pragma unroll
    for (int ks = 0; ks < 8; ++ks) {
        const int k0 = ks * 32 + kq * 8;
        bf16x8 a = *(const bf16x8*)&Hb[(w * 16 + ml) * SK + k0];
        #pragma unroll
        for (int j = 0; j < 3; ++j) {
            if (j < nct) {
                bf16x8 bf = *(const bf16x8*)&W2T[(c0 + j * 16 + ml) * 256 + k0];
                acc2[j] = __builtin_amdgcn_mfma_f32_16x16x32_bf16(a, bf, acc2[j], 0, 0, 0);
            }
        }
    }
    #pragma unroll
    for (int j = 0; j < 3; ++j) {
        if (j < nct) {
            const int col = j * 16 + ml;
            const int lim = (head == 0) ? 40 : 5;
            if (col < lim) {
                const float bias = biasF[(head == 0 ? 768 : 808) + col];
                #pragma unroll
                for (int r = 0; r < 4; ++r) {
                    const int row = bm0 + w * 16 + r0 + r;
                    const int o = (head == 0) ? row * 40 + col
                                              : 409600 + row * 5 + col;
                    const float v = acc2[j][r] + bias;
                    if (isF32) ((float*)outv)[o] = v;
                    else ((__hip_bfloat16*)outv)[o] = __float2bfloat16(v);
                }
            }
        }
    }
}

__global__ __launch_bounds__(512) void l1p_kernel(
    const void* __restrict__ Xv, const u16* __restrict__ WallT,
    const float* __restrict__ biasF,
    u16* __restrict__ P1g, u16* __restrict__ P2g)
{
    __shared__ u16 Xs[64 * SK];
    __shared__ int fcnt;
    const int t = threadIdx.x;
    const int bm0 = blockIdx.x * 64;
    const int isF32 = computeIsF32((const u16*)Xv, &fcnt, t);

    if (isF32) {
        const floatx4* __restrict__ src = (const floatx4*)((const float*)Xv + bm0 * 256);
        #pragma unroll
        for (int s = 0; s < 8; ++s) {
            int cid = t + s * 512;
            int row = cid >> 6, ch = cid & 63;
            floatx4 f = src[cid];
            ushort4v u;
            u[0] = f2bf(f[0]); u[1] = f2bf(f[1]); u[2] = f2bf(f[2]); u[3] = f2bf(f[3]);
            *(ushort4v*)&Xs[row * SK + ch * 4] = u;
        }
    } else {
        const int4v* __restrict__ src = (const int4v*)((const u16*)Xv + bm0 * 256);
        #pragma unroll
        for (int s = 0; s < 4; ++s) {
            int cid = t + s * 512;
            int row = cid >> 5, ch = cid & 31;
            *(int4v*)&Xs[row * SK + ch * 8] = src[cid];
        }
    }
    __syncthreads();

    const int w = t >> 6, l = t & 63;
    const int ml = l & 15, kq = l >> 4, r0 = kq * 4;
    const int ct = blockIdx.y * 8 + w;
    const int gc = ct * 16 + ml;

    floatx4 acc[4] = {};
    #pragma unroll
    for (int ks = 0; ks < 8; ++ks) {
        const int k0 = ks * 32 + kq * 8;
        bf16x8 bf = *(const bf16x8*)&WallT[(512 + gc) * 256 + k0];
        #pragma unroll
        for (int mt = 0; mt < 4; ++mt) {
            bf16x8 a = *(const bf16x8*)&Xs[(mt * 16 + ml) * SK + k0];
            acc[mt] = __builtin_amdgcn_mfma_f32_16x16x32_bf16(a, bf, acc[mt], 0, 0, 0);
        }
    }
    const float bias = (gc < 256) ? biasF[512 + gc] : 0.f;
    u16* __restrict__ dst = (gc < 256) ? P1g : P2g;
    const int col = gc & 255;
    #pragma unroll
    for (int mt = 0; mt < 4; ++mt)
        #pragma unroll
        for (int r = 0; r < 4; ++r)
            dst[(bm0 + mt * 16 + r0 + r) * 256 + col] = f2bf(acc[mt][r] + bias);
}

__global__ __launch_bounds__(512, 4) void pairf_kernel(
    const void* __restrict__ Xv,
    const u16* __restrict__ P1g, const u16* __restrict__ P2g,
    const void* __restrict__ Wb2, const float* __restrict__ biasF,
    void* __restrict__ outv)
{
    __shared__ u16 Pq[4][16 * SK];
    __shared__ u16 WsB[16 * 264];
    __shared__ int fcnt;
    const int t = threadIdx.x, mol = blockIdx.x;
    const int y = blockIdx.y;
    const int it = (y < 3) ? 0 : (y < 5) ? 1 : 2;
    const int jt = (y < 3) ? y : (y < 5) ? (y - 2) : 2;
    const int isF32 = computeIsF32((const u16*)Xv, &fcnt, t);

    #pragma unroll
    for (int s = 0; s < 4; ++s) {
        const int cid = t + s * 512;
        const int buf = cid >> 9, r = (cid >> 5) & 15, ch = cid & 31;
        const int tile = (buf < 2) ? it : jt;
        const u16* __restrict__ src = (buf & 1) ? P2g : P1g;
        const int arow = tile * 16 + r;
        int4v v = {0, 0, 0, 0};
        if (arow < 40) v = *(const int4v*)&src[(mol * 40 + arow) * 256 + ch * 8];
        *(int4v*)&Pq[buf][r * SK + ch * 8] = v;
    }
    #pragma unroll
    for (int s = 0; s < 8; ++s) {
        const int e2 = t + s * 512;
        const int c = e2 >> 8, k = e2 & 255;
        WsB[c * 264 + k] = (c < 5) ? ldW(Wb2, k * 5 + c, isF32) : (u16)0;
    }
    __syncthreads();

    const int w = t >> 6, l = t & 63;
    const int ml = l & 15, kq = l >> 4, r0 = kq * 4;

    bf16x8 wf[8];
    #pragma unroll
    for (int ks = 0; ks < 8; ++ks)
        wf[ks] = *(const bf16x8*)&WsB[ml * 264 + ks * 32 + kq * 8];
    const float b2x2 = 2.f * biasF[816 + ml];

    const int i0 = it * 16 + w;
    const int i1 = i0 + 8;
    const bool do1 = (it != 2);
    floatx4 acc0 = {}, acc1 = {};
    #pragma unroll
    for (int ks = 0; ks < 8; ++ks) {
        const int k0 = ks * 32 + kq * 8;
        const uint4v b1 = *(const uint4v*)&Pq[2][ml * SK + k0];
        const uint4v b2 = *(const uint4v*)&Pq[3][ml * SK + k0];
        {
            const uint4v a1 = *(const uint4v*)&Pq[0][w * SK + k0];
            const uint4v a2 = *(const uint4v*)&Pq[1][w * SK + k0];
            bf16x8 af;
            #pragma unroll
            for (int d = 0; d < 4; ++d) {
                const float sLo = lrelu(bfLo(a1[d]) + bfLo(b2[d]))
                                + lrelu(bfLo(b1[d]) + bfLo(a2[d]));
                const float sHi = lrelu(bfHi(a1[d]) + bfHi(b2[d]))
                                + lrelu(bfHi(b1[d]) + bfHi(a2[d]));
                af[2 * d]     = (short)f2bf(sLo);
                af[2 * d + 1] = (short)f2bf(sHi);
            }
            acc0 = __builtin_amdgcn_mfma_f32_16x16x32_bf16(af, wf[ks], acc0, 0, 0, 0);
        }
        if (do1) {
            const uint4v a1 = *(const uint4v*)&Pq[0][(w + 8) * SK + k0];
            const uint4v a2 = *(const uint4v*)&Pq[1][(w + 8) * SK + k0];
            bf16x8 af;
            #pragma unroll
            for (int d = 0; d < 4; ++d) {
                const float sLo = lrelu(bfLo(a1[d]) + bfLo(b2[d]))
                                + lrelu(bfLo(b1[d]) + bfLo(a2[d]));
                const float sHi = lrelu(bfHi(a1[d]) + bfHi(b2[d]))
                                + lrelu(bfHi(b1[d]) + bfHi(a2[d]));
                af[2 * d]     = (short)f2bf(sLo);
                af[2 * d + 1] = (short)f2bf(sHi);
            }
            acc1 = __builtin_amdgcn_mfma_f32_16x16x32_bf16(af, wf[ks], acc1, 0, 0, 0);
        }
    }

    if (ml < 5) {
        #pragma unroll
        for (int r = 0; r < 4; ++r) {
            const int j = jt * 16 + r0 + r;
            if (j < 40 && (it != jt || j >= i0)) {
                const float v = acc0[r] + b2x2;
                const int o1 = 460800 + (mol * 1600 + i0 * 40 + j) * 5 + ml;
                if (isF32) ((float*)outv)[o1] = v;
                else ((__hip_bfloat16*)outv)[o1] = __float2bfloat16(v);
                if (it != jt || j > i0) {
                    const int o2 = 460800 + (mol * 1600 + j * 40 + i0) * 5 + ml;
                    if (isF32) ((float*)outv)[o2] = v;
                    else ((__hip_bfloat16*)outv)[o2] = __float2bfloat16(v);
                }
            }
        }
        if (do1) {
            #pragma unroll
            for (int r = 0; r < 4; ++r) {
                const int j = jt * 16 + r0 + r;
                if (j < 40 && (it != jt || j >= i1)) {
                    const float v = acc1[r] + b2x2;
                    const int o1 = 460800 + (mol * 1600 + i1 * 40 + j) * 5 + ml;
                    if (isF32) ((float*)outv)[o1] = v;
                    else ((__hip_bfloat16*)outv)[o1] = __float2bfloat16(v);
                    if (it != jt || j > i1) {
                        const int o2 = 460800 + (mol * 1600 + j * 40 + i1) * 5 + ml;
                        if (isF32) ((float*)outv)[o2] = v;
                        else ((__hip_bfloat16*)outv)[o2] = __float2bfloat16(v);
                    }
                }
            }
        }
    }
}

__global__ __launch_bounds__(512) void bonds_kernel(
    const void* __restrict__ Xv, const u16* __restrict__ WallT,
    const void* __restrict__ Wb2, const float* __restrict__ biasF,
    void* __restrict__ outv)
{
    __shared__ u16 Xm[48 * SK];
    __shared__ u16 P1L[48 * SK];
    __shared__ u16 P2L[48 * SK];
    __shared__ u16 WsB[16 * 264];
    __shared__ float fbuf[8000];
    __shared__ int fcnt;
    const int t = threadIdx.x, b = blockIdx.x;
    const int isF32 = computeIsF32((const u16*)Xv, &fcnt, t);

    if (isF32) {
        const floatx4* __restrict__ src = (const floatx4*)((const float*)Xv + b * 10240);
        #pragma unroll
        for (int it = 0; it < 5; ++it) {
            int cid = t + it * 512;
            int row = cid >> 6, ch = cid & 63;
            floatx4 f = src[cid];
            ushort4v u;
            u[0] = f2bf(f[0]); u[1] = f2bf(f[1]); u[2] = f2bf(f[2]); u[3] = f2bf(f[3]);
            *(ushort4v*)&Xm[row * SK + ch * 4] = u;
        }
        {
            int row = 40 + (t >> 6), ch = t & 63;
            ushort4v z = {0, 0, 0, 0};
            *(ushort4v*)&Xm[row * SK + ch * 4] = z;
        }
    } else {
        const int4v* __restrict__ src = (const int4v*)((const u16*)Xv + b * 10240);
        #pragma unroll
        for (int it = 0; it < 3; ++it) {
            int cid = t + it * 512;
            int row = cid >> 5, ch = cid & 31;
            if (cid < 1280) *(int4v*)&Xm[row * SK + ch * 8] = src[cid];
            else { int4v z = {0, 0, 0, 0}; *(int4v*)&Xm[row * SK + ch * 8] = z; }
        }
    }
    #pragma unroll
    for (int it = 0; it < 8; ++it) {
        int e2 = t + it * 512;
        int c = e2 >> 8, k = e2 & 255;
        WsB[c * 264 + k] = (c < 5) ? ldW(Wb2, k * 5 + c, isF32) : (u16)0;
    }
    __syncthreads();

    const int w = t >> 6, l = t & 63;
    const int ml = l & 15, kq = l >> 4, r0 = kq * 4;

    for (int n = 0; n < 4; ++n) {
        const int gc = (w + 8 * n) * 16 + ml;
        floatx4 acc[3] = {};
        #pragma unroll
        for (int ks = 0; ks < 8; ++ks) {
            const int k0 = ks * 32 + kq * 8;
            bf16x8 bf = *(const bf16x8*)&WallT[(512 + gc) * 256 + k0];
            #pragma unroll
            for (int i = 0; i < 3; ++i) {
                bf16x8 a = *(const bf16x8*)&Xm[(i * 16 + ml) * SK + k0];
                acc[i] = __builtin_amdgcn_mfma_f32_16x16x32_bf16(a, bf, acc[i], 0, 0, 0);
            }
        }
        u16* dst = (gc < 256) ? P1L : P2L;
        const int col = gc & 255;
        const float bias = (gc < 256) ? biasF[512 + gc] : 0.f;
        #pragma unroll
        for (int i = 0; i < 3; ++i)
            #pragma unroll
            for (int r = 0; r < 4; ++r)
                dst[(i * 16 + r0 + r) * SK + col] = f2bf(acc[i][r] + bias);
    }
    __syncthreads();

    bf16x8 wf[8];
    #pragma unroll
    for (int ks = 0; ks < 8; ++ks)
        wf[ks] = *(const bf16x8*)&WsB[ml * 264 + ks * 32 + kq * 8];

    for (int m = 0; m < 5; ++m) {
        const int i = w + 8 * m;
        uint4v pa8[8];
        #pragma unroll
        for (int ks = 0; ks < 8; ++ks)
            pa8[ks] = *(const uint4v*)&P1L[i * SK + ks * 32 + kq * 8];
        for (int jt = 0; jt < 3; ++jt) {
            floatx4 acc = {};
            #pragma unroll
            for (int ks = 0; ks < 8; ++ks) {
                const int k0 = ks * 32 + kq * 8;
                uint4v pa = pa8[ks];
                uint4v pb = *(const uint4v*)&P2L[(jt * 16 + ml) * SK + k0];
                bf16x8 af;
                #pragma unroll
                for (int d = 0; d < 4; ++d) {
                    af[2 * d]     = (short)f2bf(lrelu(bfLo(pa[d]) + bfLo(pb[d])));
                    af[2 * d + 1] = (short)f2bf(lrelu(bfHi(pa[d]) + bfHi(pb[d])));
                }
                acc = __builtin_amdgcn_mfma_f32_16x16x32_bf16(af, wf[ks], acc, 0, 0, 0);
            }
            if (ml < 5) {
                #pragma unroll
                for (int r = 0; r < 4; ++r) {
                    const int j = jt * 16 + r0 + r;
                    if (j < 40) fbuf[(i * 40 + j) * 5 + ml] = acc[r];
                }
            }
        }
    }
    __syncthreads();

    const int base = 460800 + b * 8000;
    for (int e = t; e < 8000; e += 512) {
        int pr = e / 5, c = e - pr * 5;
        int i = pr / 40, j = pr - (pr / 40) * 40;
        float v = fbuf[e] + fbuf[(j * 40 + i) * 5 + c] + 2.f * biasF[816 + c];
        if (isF32) ((float*)outv)[base + e] = v;
        else ((__hip_bfloat16*)outv)[base + e] = __float2bfloat16(v);
    }
}

// ---------------------------------------------------------------------------
extern "C" void kernel_launch(void* const* d_in, const int* in_sizes, int n_in,
                              void* d_out, int out_size, void* d_ws, size_t ws_size,
                              hipStream_t stream)
{
    const void* yhat = d_in[0];
    const void* Ws1  = d_in[1];
    const void* bs1  = d_in[2];
    const void* Ws2  = d_in[3];
    const void* bs2  = d_in[4];
    const void* Wc1  = d_in[5];
    const void* bc1  = d_in[6];
    const void* Wc2  = d_in[7];
    const void* bc2  = d_in[8];
    const void* Wb1  = d_in[9];
    const void* bb1  = d_in[10];
    const void* Wb2  = d_in[11];
    const void* bb2  = d_in[12];

    char* wsb = (char*)d_ws;
    float* biasF = (float*)(wsb + 4096);
    u16*   W2T   = (u16*)(wsb + 8192);
    u16*   WallT = (u16*)(wsb + 40960);
    const size_t P_BYTES = (size_t)10240 * 256 * 2;     // 5242880
    u16* P1g = (u16*)(wsb + 565248);
    u16* P2g = (u16*)(wsb + 565248 + P_BYTES);
    const bool big = ws_size >= 565248 + 2 * P_BYTES;   // 11,051,008 B

    bool coopDone = false;
    if (big) {
        static int megaBlocks = -2;
        if (megaBlocks == -2) {
            int occ = 0;
            if (hipOccupancyMaxActiveBlocksPerMultiprocessor(
                    &occ, (const void*)mega_kernel, 512, 0) != hipSuccess || occ < 1)
                occ = 1;
            int nCU = 256;
            hipDeviceProp_t props;
            int dev = 0;
            if (hipGetDevice(&dev) == hipSuccess &&
                hipGetDeviceProperties(&props, dev) == hipSuccess &&
                props.multiProcessorCount > 0)
                nCU = props.multiProcessorCount;
            megaBlocks = occ * nCU;
        }
        void* kargs[] = {
            (void*)&yhat, (void*)&Ws1, (void*)&Wc1, (void*)&Wb1,
            (void*)&Ws2, (void*)&Wc2,
            (void*)&bs1, (void*)&bc1, (void*)&bb1,
            (void*)&bs2, (void*)&bc2, (void*)&bb2,
            (void*)&Wb2,
            (void*)&WallT, (void*)&W2T, (void*)&biasF,
            (void*)&P1g, (void*)&P2g, (void*)&d_out
        };
        hipError_t e = hipLaunchCooperativeKernel(
            (const void*)mega_kernel, dim3(megaBlocks), dim3(512), kargs, 0, stream);
        if (e == hipSuccess) coopDone = true;
        else (void)hipGetLastError();   // clear error, fall back
    }

    if (!coopDone) {
        pack_kernel<<<132, 256, 0, stream>>>(yhat, Ws1, Wc1, Wb1, Ws2, Wc2,
                                             bs1, bc1, bb1, bs2, bc2, bb2,
                                             WallT, W2T, biasF);
        heads_kernel<<<dim3(160, 2), 256, 0, stream>>>(yhat, WallT, W2T, biasF, d_out);
        if (big) {
            l1p_kernel<<<dim3(160, 4), 512, 0, stream>>>(yhat, WallT, biasF, P1g, P2g);
            pairf_kernel<<<dim3(256, 6), 512, 0, stream>>>(yhat, P1g, P2g, Wb2,
                                                           biasF, d_out);
        } else {
            bonds_kernel<<<256, 512, 0, stream>>>(yhat, WallT, Wb2, biasF, d_out);
        }
    }
}

// Round 5
// 146.504 us; speedup vs baseline: 1.6292x; 1.6292x over previous
//
#include <hip/hip_runtime.h>
#include <hip/hip_bf16.h>

typedef unsigned short u16;
typedef __attribute__((ext_vector_type(4))) int   int4v;
typedef __attribute__((ext_vector_type(4))) unsigned int uint4v;
typedef __attribute__((ext_vector_type(4))) unsigned short ushort4v;
typedef __attribute__((ext_vector_type(4))) float floatx4;
typedef __attribute__((ext_vector_type(8))) short bf16x8;

#define LRELU_NS 0.01f
#define SK 264   // LDS k-stride (bf16): 256 + 8 pad, 16B-aligned rows

__device__ __forceinline__ float bitsToF(unsigned int b) {
    union { unsigned int u; float f; } v; v.u = b << 16; return v.f;
}
__device__ __forceinline__ float bfLo(unsigned int d) {
    union { unsigned int u; float f; } v; v.u = d << 16; return v.f;
}
__device__ __forceinline__ float bfHi(unsigned int d) {
    union { unsigned int u; float f; } v; v.u = d & 0xffff0000u; return v.f;
}
__device__ __forceinline__ u16 f2bf(float f) {
    __hip_bfloat16 h = __float2bfloat16(f);
    return *reinterpret_cast<u16*>(&h);
}
// 2-op leaky relu: max(x, 0.01x) == (x>=0 ? x : 0.01x) for all finite x
__device__ __forceinline__ float lrelu(float v) {
    return fmaxf(v, LRELU_NS * v);
}
__device__ __forceinline__ u16 ldW(const void* p, int i, int isF32) {
    return isF32 ? f2bf(((const float*)p)[i]) : ((const u16*)p)[i];
}
__device__ __forceinline__ float ldF(const void* p, int i, int isF32) {
    return isF32 ? ((const float*)p)[i]
                 : bitsToF((unsigned int)((const u16*)p)[i]);
}

// dtype probe (verified) — all threads of the block must call.
__device__ __forceinline__ int computeIsF32(const u16* y, int* cnt, int t) {
    if (t == 0) *cnt = 0;
    __syncthreads();
    if (t < 256) {
        u16 v = y[2 * t];
        int e = (v >> 7) & 0xFF;
        if (v == 0 || (e >= 96 && e < 160)) atomicAdd(cnt, 1);
    }
    __syncthreads();
    return (*cnt < 192) ? 1 : 0;
}

// ---------------------------------------------------------------------------
// Kernel 1: pack — verbatim R0 (verified).
// blocks 0..63: WallT 64x64 transpose tiles; 64..127: W2T; 128..131: biasF.
// ---------------------------------------------------------------------------
__global__ __launch_bounds__(256) void pack_kernel(
    const void* __restrict__ yhat,
    const void* __restrict__ Ws1, const void* __restrict__ Wc1,
    const void* __restrict__ Wb1, const void* __restrict__ Ws2,
    const void* __restrict__ Wc2,
    const void* __restrict__ bs1, const void* __restrict__ bc1,
    const void* __restrict__ bb1, const void* __restrict__ bs2,
    const void* __restrict__ bc2, const void* __restrict__ bb2,
    u16* __restrict__ WallT, u16* __restrict__ W2T, float* __restrict__ biasF)
{
    __shared__ int fcnt;
    const int bid = blockIdx.x, t = threadIdx.x;
    const int isF32 = computeIsF32((const u16*)yhat, &fcnt, t);
    if (bid < 64) {
        __shared__ u16 tile[64][65];
        const int c0 = (bid & 15) * 64;      // col-tile in [0,1024)
        const int k0 = (bid >> 4) * 64;      // k-tile in [0,256)
        const void* src; int coff; int roff = 0;
        if (c0 < 256)      { src = Ws1; coff = c0; }
        else if (c0 < 512) { src = Wc1; coff = c0 - 256; }
        else if (c0 < 768) { src = Wb1; coff = c0 - 512; }
        else               { src = Wb1; coff = c0 - 768; roff = 256; }
        const int cc = t & 63, kk0 = t >> 6;
        #pragma unroll
        for (int i = 0; i < 16; ++i) {
            int kk = kk0 + i * 4;
            tile[kk][cc] = ldW(src, (k0 + kk + roff) * 256 + coff + cc, isF32);
        }
        __syncthreads();
        const int kk2 = t & 63, cc0 = t >> 6;
        #pragma unroll
        for (int i = 0; i < 16; ++i) {
            int cc2 = cc0 + i * 4;
            WallT[(c0 + cc2) * 256 + (k0 + kk2)] = tile[kk2][cc2];
        }
    } else if (bid < 128) {
        int e2 = (bid - 64) * 256 + t;       // < 16384
        int c = e2 >> 8, k = e2 & 255;
        u16 v = 0;
        if (c < 40)                 v = ldW(Ws2, k * 40 + c, isF32);
        else if (c >= 48 && c < 53) v = ldW(Wc2, k * 5 + (c - 48), isF32);
        W2T[c * 256 + k] = v;
    } else {
        int idx = (bid - 128) * 256 + t;     // < 1024
        float v = 0.f;
        if (idx < 256)       v = ldF(bs1, idx, isF32);
        else if (idx < 512)  v = ldF(bc1, idx - 256, isF32);
        else if (idx < 768)  v = ldF(bb1, idx - 512, isF32);
        else if (idx < 808)  v = ldF(bs2, idx - 768, isF32);
        else if (idx < 813)  v = ldF(bc2, idx - 808, isF32);
        else if (idx >= 816 && idx < 821) v = ldF(bb2, idx - 816, isF32);
        biasF[idx] = v;
    }
}

// ---------------------------------------------------------------------------
// Kernel 2: heads2 — symbols + charges, 512 threads (8 waves, was 4).
// Body = mega phase-1 y<2 (harness-verified in R4's passing mega run).
// L1: 16 col-tiles over 8 waves (n=2); L2: waves 0..3. grid (160, 2).
// LDS 67.6 KB -> 2 blocks/CU -> 16 waves/CU (was 8 at 256 thr).
// ---------------------------------------------------------------------------
__global__ __launch_bounds__(512) void heads2_kernel(
    const void* __restrict__ Xv, const u16* __restrict__ WallT,
    const u16* __restrict__ W2T, const float* __restrict__ biasF,
    void* __restrict__ outv)
{
    __shared__ u16 Xs[64 * SK];
    __shared__ u16 Hb[64 * SK];
    __shared__ int fcnt;
    const int t = threadIdx.x;
    const int bm0 = blockIdx.x * 64;
    const int head = blockIdx.y;
    const int isF32 = computeIsF32((const u16*)Xv, &fcnt, t);

    if (isF32) {   // stage X tile [64][256] from fp32, cvt to bf16
        const floatx4* __restrict__ src = (const floatx4*)((const float*)Xv + bm0 * 256);
        #pragma unroll
        for (int s = 0; s < 8; ++s) {
            int cid = t + s * 512;             // < 4096 chunks of 4 floats
            int row = cid >> 6, ch = cid & 63;
            floatx4 f = src[cid];
            ushort4v u;
            u[0] = f2bf(f[0]); u[1] = f2bf(f[1]); u[2] = f2bf(f[2]); u[3] = f2bf(f[3]);
            *(ushort4v*)&Xs[row * SK + ch * 4] = u;
        }
    } else {       // stage X tile from bf16
        const int4v* __restrict__ src = (const int4v*)((const u16*)Xv + bm0 * 256);
        #pragma unroll
        for (int s = 0; s < 4; ++s) {
            int cid = t + s * 512;             // < 2048 chunks of 8 bf16
            int row = cid >> 5, ch = cid & 31;
            *(int4v*)&Xs[row * SK + ch * 8] = src[cid];
        }
    }
    __syncthreads();

    const int w = t >> 6, l = t & 63;
    const int ml = l & 15, kq = l >> 4, r0 = kq * 4;

    // ---- layer 1: 16 col-tiles over 8 waves; 4 M-tiles each ----
    #pragma unroll
    for (int n = 0; n < 2; ++n) {
        const int ct = w + 8 * n;              // [0,16)
        floatx4 acc[4] = {};
        #pragma unroll
        for (int ks = 0; ks < 8; ++ks) {
            const int k0 = ks * 32 + kq * 8;
            bf16x8 bf = *(const bf16x8*)&WallT[(head * 256 + ct * 16 + ml) * 256 + k0];
            #pragma unroll
            for (int mt = 0; mt < 4; ++mt) {
                bf16x8 a = *(const bf16x8*)&Xs[(mt * 16 + ml) * SK + k0];
                acc[mt] = __builtin_amdgcn_mfma_f32_16x16x32_bf16(a, bf, acc[mt], 0, 0, 0);
            }
        }
        const int col = ct * 16 + ml;          // [0,256)
        const float bias = biasF[head * 256 + col];   // bs1 | bc1
        #pragma unroll
        for (int mt = 0; mt < 4; ++mt)
            #pragma unroll
            for (int r = 0; r < 4; ++r)
                Hb[(mt * 16 + r0 + r) * SK + col] = f2bf(lrelu(acc[mt][r] + bias));
    }
    __syncthreads();   // Hb complete

    // ---- layer 2: waves 0..3 own M-tile w ----
    if (w < 4) {
        const int nct = (head == 0) ? 3 : 1;   // block-uniform
        const int c0  = (head == 0) ? 0 : 48;
        floatx4 acc2[3] = {};
        #pragma unroll
        for (int ks = 0; ks < 8; ++ks) {
            const int k0 = ks * 32 + kq * 8;
            bf16x8 a = *(const bf16x8*)&Hb[(w * 16 + ml) * SK + k0];
            #pragma unroll
            for (int j = 0; j < 3; ++j) {
                if (j < nct) {
                    bf16x8 bf = *(const bf16x8*)&W2T[(c0 + j * 16 + ml) * 256 + k0];
                    acc2[j] = __builtin_amdgcn_mfma_f32_16x16x32_bf16(a, bf, acc2[j], 0, 0, 0);
                }
            }
        }
        #pragma unroll
        for (int j = 0; j < 3; ++j) {
            if (j < nct) {
                const int col = j * 16 + ml;
                const int lim = (head == 0) ? 40 : 5;
                if (col < lim) {
                    const float bias = biasF[(head == 0 ? 768 : 808) + col];
                    #pragma unroll
                    for (int r = 0; r < 4; ++r) {
                        const int row = bm0 + w * 16 + r0 + r;
                        const int o = (head == 0) ? row * 40 + col
                                                  : 409600 + row * 5 + col;
                        const float v = acc2[j][r] + bias;
                        if (isF32) ((float*)outv)[o] = v;
                        else ((__hip_bfloat16*)outv)[o] = __float2bfloat16(v);
                    }
                }
            }
        }
    }
}

// ---------------------------------------------------------------------------
// Kernel 3: bonds2 — monolith (1 molecule/block) with verified L1, then a
// fused dual-direction pair phase (pairf-verified math, P from LDS):
//   out[i][j] = out[j][i] = sum_k( lrelu(P1i+P2j) + lrelu(P1j+P2i) )*W + 2*bb2
// computed for unordered tile pairs jt >= i>>4, written direct + mirror.
// Deltas vs R0 bonds: no fbuf (32 KB), no 3rd barrier, WsB 16->5 rows
// (B cols >=5 feed discarded D cols; lanes ml>=5 read row 4, don't-care).
// LDS 116.5 -> 78.7 KB  =>  2 blocks/CU (was 1), 16 waves/CU.
// ---------------------------------------------------------------------------
__global__ __launch_bounds__(512) void bonds2_kernel(
    const void* __restrict__ Xv, const u16* __restrict__ WallT,
    const void* __restrict__ Wb2, const float* __restrict__ biasF,
    void* __restrict__ outv)
{
    __shared__ u16 Xm[48 * SK];
    __shared__ u16 P1L[48 * SK];
    __shared__ u16 P2L[48 * SK];
    __shared__ u16 WsB[5 * 264];
    __shared__ int fcnt;
    const int t = threadIdx.x, b = blockIdx.x;
    const int isF32 = computeIsF32((const u16*)Xv, &fcnt, t);

    if (isF32) {   // stage X rows 0..39 (fp32 -> bf16), zero rows 40..47
        const floatx4* __restrict__ src = (const floatx4*)((const float*)Xv + b * 10240);
        #pragma unroll
        for (int s = 0; s < 5; ++s) {
            int cid = t + s * 512;             // 2560 chunks of 4 floats
            int row = cid >> 6, ch = cid & 63;
            floatx4 f = src[cid];
            ushort4v u;
            u[0] = f2bf(f[0]); u[1] = f2bf(f[1]); u[2] = f2bf(f[2]); u[3] = f2bf(f[3]);
            *(ushort4v*)&Xm[row * SK + ch * 4] = u;
        }
        {   // zero rows 40..47
            int row = 40 + (t >> 6), ch = t & 63;
            ushort4v z = {0, 0, 0, 0};
            *(ushort4v*)&Xm[row * SK + ch * 4] = z;
        }
    } else {
        const int4v* __restrict__ src = (const int4v*)((const u16*)Xv + b * 10240);
        #pragma unroll
        for (int s = 0; s < 3; ++s) {
            int cid = t + s * 512;             // < 1536
            int row = cid >> 5, ch = cid & 31;
            if (cid < 1280) *(int4v*)&Xm[row * SK + ch * 8] = src[cid];
            else { int4v z = {0, 0, 0, 0}; *(int4v*)&Xm[row * SK + ch * 8] = z; }
        }
    }
    // Wb2[256][5] -> WsB[c][k] bf16, c<5 only
    #pragma unroll
    for (int s = 0; s < 3; ++s) {
        int e2 = t + s * 512;                  // < 1536
        if (e2 < 1280) {
            int c = e2 >> 8, k = e2 & 255;
            WsB[c * 264 + k] = ldW(Wb2, k * 5 + c, isF32);
        }
    }
    __syncthreads();   // Xm + WsB visible

    const int w = t >> 6, l = t & 63;
    const int ml = l & 15, kq = l >> 4, r0 = kq * 4;

    // ---- layer 1 (verbatim R0 bonds): P = X @ Wb1 (+bb1 on P1 half) ----
    for (int n = 0; n < 4; ++n) {
        const int gc = (w + 8 * n) * 16 + ml;  // [0,512)
        floatx4 acc[3] = {};
        #pragma unroll
        for (int ks = 0; ks < 8; ++ks) {
            const int k0 = ks * 32 + kq * 8;
            bf16x8 bf = *(const bf16x8*)&WallT[(512 + gc) * 256 + k0];
            #pragma unroll
            for (int i = 0; i < 3; ++i) {
                bf16x8 a = *(const bf16x8*)&Xm[(i * 16 + ml) * SK + k0];
                acc[i] = __builtin_amdgcn_mfma_f32_16x16x32_bf16(a, bf, acc[i], 0, 0, 0);
            }
        }
        u16* dst = (gc < 256) ? P1L : P2L;
        const int col = gc & 255;
        const float bias = (gc < 256) ? biasF[512 + gc] : 0.f;   // bb1 on P1
        #pragma unroll
        for (int i = 0; i < 3; ++i)
            #pragma unroll
            for (int r = 0; r < 4; ++r)
                dst[(i * 16 + r0 + r) * SK + col] = f2bf(acc[i][r] + bias);
    }
    __syncthreads();

    // ---- dual-direction pair phase, no fbuf ----
    const int sel = (ml < 5) ? ml : 4;         // ml>=5 feeds discarded D cols
    bf16x8 wf[8];
    #pragma unroll
    for (int ks = 0; ks < 8; ++ks)
        wf[ks] = *(const bf16x8*)&WsB[sel * 264 + ks * 32 + kq * 8];
    const float b2x2 = 2.f * biasF[816 + ml];  // ml>=5 reads zeros (in-bounds)

    for (int m = 0; m < 5; ++m) {
        const int i = w + 8 * m;               // [0,40)
        const int itile = i >> 4;              // wave-uniform per m
        for (int jt = itile; jt < 3; ++jt) {   // unordered tile pairs only
            floatx4 accF = {}, accB = {};
            #pragma unroll
            for (int ks = 0; ks < 8; ++ks) {
                const int k0 = ks * 32 + kq * 8;
                const uint4v a1 = *(const uint4v*)&P1L[i * SK + k0];             // P1[i]
                const uint4v a2 = *(const uint4v*)&P2L[i * SK + k0];             // P2[i]
                const uint4v b1 = *(const uint4v*)&P1L[(jt * 16 + ml) * SK + k0]; // P1[j]
                const uint4v b2 = *(const uint4v*)&P2L[(jt * 16 + ml) * SK + k0]; // P2[j]
                bf16x8 afF, afB;
                #pragma unroll
                for (int d = 0; d < 4; ++d) {
                    afF[2 * d]     = (short)f2bf(lrelu(bfLo(a1[d]) + bfLo(b2[d])));
                    afF[2 * d + 1] = (short)f2bf(lrelu(bfHi(a1[d]) + bfHi(b2[d])));
                    afB[2 * d]     = (short)f2bf(lrelu(bfLo(b1[d]) + bfLo(a2[d])));
                    afB[2 * d + 1] = (short)f2bf(lrelu(bfHi(b1[d]) + bfHi(a2[d])));
                }
                accF = __builtin_amdgcn_mfma_f32_16x16x32_bf16(afF, wf[ks], accF, 0, 0, 0);
                accB = __builtin_amdgcn_mfma_f32_16x16x32_bf16(afB, wf[ks], accB, 0, 0, 0);
            }
            if (ml < 5) {                      // D: row=kq*4+r -> j, col=ml -> class
                const bool diag = (jt == itile);
                #pragma unroll
                for (int r = 0; r < 4; ++r) {
                    const int j = jt * 16 + r0 + r;
                    if (j < 40 && (!diag || j >= i)) {
                        const float v = accF[r] + accB[r] + b2x2;
                        const int o1 = 460800 + (b * 1600 + i * 40 + j) * 5 + ml;
                        if (isF32) ((float*)outv)[o1] = v;
                        else ((__hip_bfloat16*)outv)[o1] = __float2bfloat16(v);
                        if (!diag || j > i) {
                            const int o2 = 460800 + (b * 1600 + j * 40 + i) * 5 + ml;
                            if (isF32) ((float*)outv)[o2] = v;
                            else ((__hip_bfloat16*)outv)[o2] = __float2bfloat16(v);
                        }
                    }
                }
            }
        }
    }
}

// ---------------------------------------------------------------------------
extern "C" void kernel_launch(void* const* d_in, const int* in_sizes, int n_in,
                              void* d_out, int out_size, void* d_ws, size_t ws_size,
                              hipStream_t stream)
{
    const void* yhat = d_in[0];
    const void* Ws1  = d_in[1];
    const void* bs1  = d_in[2];
    const void* Ws2  = d_in[3];
    const void* bs2  = d_in[4];
    const void* Wc1  = d_in[5];
    const void* bc1  = d_in[6];
    const void* Wc2  = d_in[7];
    const void* bc2  = d_in[8];
    const void* Wb1  = d_in[9];
    const void* bb1  = d_in[10];
    const void* Wb2  = d_in[11];
    const void* bb2  = d_in[12];

    // workspace: 565248 bytes total (same as verified R0 layout)
    char* wsb = (char*)d_ws;
    float* biasF = (float*)(wsb + 4096);     // 1024 floats
    u16*   W2T   = (u16*)(wsb + 8192);       // 64*256 bf16  = 32768 B
    u16*   WallT = (u16*)(wsb + 40960);      // 1024*256 bf16 = 524288 B

    pack_kernel<<<132, 256, 0, stream>>>(yhat, Ws1, Wc1, Wb1, Ws2, Wc2,
                                         bs1, bc1, bb1, bs2, bc2, bb2,
                                         WallT, W2T, biasF);
    heads2_kernel<<<dim3(160, 2), 512, 0, stream>>>(yhat, WallT, W2T, biasF, d_out);
    bonds2_kernel<<<256, 512, 0, stream>>>(yhat, WallT, Wb2, biasF, d_out);
}

// Round 7
// 140.441 us; speedup vs baseline: 1.6995x; 1.0432x over previous
//
#include <hip/hip_runtime.h>
#include <hip/hip_bf16.h>

typedef unsigned short u16;
typedef __attribute__((ext_vector_type(4))) int   int4v;
typedef __attribute__((ext_vector_type(4))) unsigned int uint4v;
typedef __attribute__((ext_vector_type(4))) unsigned short ushort4v;
typedef __attribute__((ext_vector_type(4))) float floatx4;
typedef __attribute__((ext_vector_type(8))) short bf16x8;
typedef _Float16 half8 __attribute__((ext_vector_type(8)));
typedef _Float16 half2v __attribute__((ext_vector_type(2)));

#define LRELU_NS 0.01f
#define SK 264   // LDS k-stride (u16 units): 256 + 8 pad, 16B-aligned rows

__device__ __forceinline__ float bitsToF(unsigned int b) {
    union { unsigned int u; float f; } v; v.u = b << 16; return v.f;
}
__device__ __forceinline__ u16 f2bf(float f) {
    __hip_bfloat16 h = __float2bfloat16(f);
    return *reinterpret_cast<u16*>(&h);
}
// 2-op leaky relu (f32): max(x, 0.01x) — exact for all finite x
__device__ __forceinline__ float lrelu(float v) {
    return fmaxf(v, LRELU_NS * v);
}
__device__ __forceinline__ u16 ldW(const void* p, int i, int isF32) {
    return isF32 ? f2bf(((const float*)p)[i]) : ((const u16*)p)[i];
}
__device__ __forceinline__ float ldF(const void* p, int i, int isF32) {
    return isF32 ? ((const float*)p)[i]
                 : bitsToF((unsigned int)((const u16*)p)[i]);
}
// float -> fp16 bits (native _Float16 cast = round-to-nearest-even)
__device__ __forceinline__ u16 f2h_bits(float f) {
    union { _Float16 h; u16 u; } v; v.h = (_Float16)f; return v.u;
}
// load -> fp16 bits (for the f16 pair path)
__device__ __forceinline__ u16 ldWh(const void* p, int i, int isF32) {
    float f = isF32 ? ((const float*)p)[i]
                    : bitsToF((unsigned int)((const u16*)p)[i]);
    return f2h_bits(f);
}
__device__ __forceinline__ half2v u2h2(unsigned int x) {
    union { unsigned int u; half2v h; } v; v.u = x; return v.h;
}
__device__ __forceinline__ unsigned int h22u(half2v x) {
    union { half2v h; unsigned int u; } v; v.h = x; return v.u;
}

// dtype probe (verified) — all threads of the block must call.
__device__ __forceinline__ int computeIsF32(const u16* y, int* cnt, int t) {
    if (t == 0) *cnt = 0;
    __syncthreads();
    if (t < 256) {
        u16 v = y[2 * t];
        int e = (v >> 7) & 0xFF;
        if (v == 0 || (e >= 96 && e < 160)) atomicAdd(cnt, 1);
    }
    __syncthreads();
    return (*cnt < 192) ? 1 : 0;
}

// ---------------------------------------------------------------------------
// Kernel 1: pack — verbatim R0 (verified).
// ---------------------------------------------------------------------------
__global__ __launch_bounds__(256) void pack_kernel(
    const void* __restrict__ yhat,
    const void* __restrict__ Ws1, const void* __restrict__ Wc1,
    const void* __restrict__ Wb1, const void* __restrict__ Ws2,
    const void* __restrict__ Wc2,
    const void* __restrict__ bs1, const void* __restrict__ bc1,
    const void* __restrict__ bb1, const void* __restrict__ bs2,
    const void* __restrict__ bc2, const void* __restrict__ bb2,
    u16* __restrict__ WallT, u16* __restrict__ W2T, float* __restrict__ biasF)
{
    __shared__ int fcnt;
    const int bid = blockIdx.x, t = threadIdx.x;
    const int isF32 = computeIsF32((const u16*)yhat, &fcnt, t);
    if (bid < 64) {
        __shared__ u16 tile[64][65];
        const int c0 = (bid & 15) * 64;      // col-tile in [0,1024)
        const int k0 = (bid >> 4) * 64;      // k-tile in [0,256)
        const void* src; int coff; int roff = 0;
        if (c0 < 256)      { src = Ws1; coff = c0; }
        else if (c0 < 512) { src = Wc1; coff = c0 - 256; }
        else if (c0 < 768) { src = Wb1; coff = c0 - 512; }
        else               { src = Wb1; coff = c0 - 768; roff = 256; }
        const int cc = t & 63, kk0 = t >> 6;
        #pragma unroll
        for (int i = 0; i < 16; ++i) {
            int kk = kk0 + i * 4;
            tile[kk][cc] = ldW(src, (k0 + kk + roff) * 256 + coff + cc, isF32);
        }
        __syncthreads();
        const int kk2 = t & 63, cc0 = t >> 6;
        #pragma unroll
        for (int i = 0; i < 16; ++i) {
            int cc2 = cc0 + i * 4;
            WallT[(c0 + cc2) * 256 + (k0 + kk2)] = tile[kk2][cc2];
        }
    } else if (bid < 128) {
        int e2 = (bid - 64) * 256 + t;       // < 16384
        int c = e2 >> 8, k = e2 & 255;
        u16 v = 0;
        if (c < 40)                 v = ldW(Ws2, k * 40 + c, isF32);
        else if (c >= 48 && c < 53) v = ldW(Wc2, k * 5 + (c - 48), isF32);
        W2T[c * 256 + k] = v;
    } else {
        int idx = (bid - 128) * 256 + t;     // < 1024
        float v = 0.f;
        if (idx < 256)       v = ldF(bs1, idx, isF32);
        else if (idx < 512)  v = ldF(bc1, idx - 256, isF32);
        else if (idx < 768)  v = ldF(bb1, idx - 512, isF32);
        else if (idx < 808)  v = ldF(bs2, idx - 768, isF32);
        else if (idx < 813)  v = ldF(bc2, idx - 808, isF32);
        else if (idx >= 816 && idx < 821) v = ldF(bb2, idx - 816, isF32);
        biasF[idx] = v;
    }
}

// ---------------------------------------------------------------------------
// Kernel 2: heads — verbatim R0 (verified best composition, 139.1 us).
// ---------------------------------------------------------------------------
__global__ __launch_bounds__(256) void heads_kernel(
    const void* __restrict__ Xv, const u16* __restrict__ WallT,
    const u16* __restrict__ W2T, const float* __restrict__ biasF,
    void* __restrict__ outv)
{
    __shared__ u16 Xs[64 * SK];
    __shared__ u16 Hb[64 * SK];
    __shared__ int fcnt;
    const int t = threadIdx.x;
    const int bm0 = blockIdx.x * 64;
    const int head = blockIdx.y;
    const int isF32 = computeIsF32((const u16*)Xv, &fcnt, t);

    if (isF32) {   // stage X tile [64][256] from fp32, cvt to bf16
        const floatx4* __restrict__ src = (const floatx4*)((const float*)Xv + bm0 * 256);
        #pragma unroll
        for (int it = 0; it < 16; ++it) {
            int cid = t + it * 256;            // 4096 chunks of 4 floats
            int row = cid >> 6, ch = cid & 63;
            floatx4 f = src[cid];
            ushort4v u;
            u[0] = f2bf(f[0]); u[1] = f2bf(f[1]); u[2] = f2bf(f[2]); u[3] = f2bf(f[3]);
            *(ushort4v*)&Xs[row * SK + ch * 4] = u;
        }
    } else {       // stage X tile from bf16
        const int4v* __restrict__ src = (const int4v*)((const u16*)Xv + bm0 * 256);
        #pragma unroll
        for (int it = 0; it < 8; ++it) {
            int cid = t + it * 256;            // 2048 chunks of 8 bf16
            int row = cid >> 5, ch = cid & 31;
            *(int4v*)&Xs[row * SK + ch * 8] = src[cid];
        }
    }
    __syncthreads();

    const int w = t >> 6, l = t & 63;
    const int ml = l & 15, kq = l >> 4, r0 = kq * 4;

    // ---- layer 1: 16 col-tiles; wave does ct = w+4n; 4 M-tiles each ----
    for (int n = 0; n < 4; ++n) {
        const int ct = w + 4 * n;
        floatx4 acc[4] = {};
        #pragma unroll
        for (int ks = 0; ks < 8; ++ks) {
            const int k0 = ks * 32 + kq * 8;
            bf16x8 bf = *(const bf16x8*)&WallT[(head * 256 + ct * 16 + ml) * 256 + k0];
            #pragma unroll
            for (int mt = 0; mt < 4; ++mt) {
                bf16x8 a = *(const bf16x8*)&Xs[(mt * 16 + ml) * SK + k0];
                acc[mt] = __builtin_amdgcn_mfma_f32_16x16x32_bf16(a, bf, acc[mt], 0, 0, 0);
            }
        }
        const int col = ct * 16 + ml;          // [0,256)
        const float bias = biasF[head * 256 + col];   // bs1 | bc1
        #pragma unroll
        for (int mt = 0; mt < 4; ++mt)
            #pragma unroll
            for (int r = 0; r < 4; ++r)
                Hb[(mt * 16 + r0 + r) * SK + col] = f2bf(lrelu(acc[mt][r] + bias));
    }
    __syncthreads();   // Hb complete

    // ---- layer 2: wave w owns M-tile mt = w ----
    const int nct = (head == 0) ? 3 : 1;       // block-uniform
    const int c0  = (head == 0) ? 0 : 48;
    floatx4 acc2[3] = {};
    #pragma unroll
    for (int ks = 0; ks < 8; ++ks) {
        const int k0 = ks * 32 + kq * 8;
        bf16x8 a = *(const bf16x8*)&Hb[(w * 16 + ml) * SK + k0];
        #pragma unroll
        for (int j = 0; j < 3; ++j) {
            if (j < nct) {
                bf16x8 bf = *(const bf16x8*)&W2T[(c0 + j * 16 + ml) * 256 + k0];
                acc2[j] = __builtin_amdgcn_mfma_f32_16x16x32_bf16(a, bf, acc2[j], 0, 0, 0);
            }
        }
    }
    #pragma unroll
    for (int j = 0; j < 3; ++j) {
        if (j < nct) {
            const int col = j * 16 + ml;
            const int lim = (head == 0) ? 40 : 5;
            if (col < lim) {
                const float bias = biasF[(head == 0 ? 768 : 808) + col];
                #pragma unroll
                for (int r = 0; r < 4; ++r) {
                    const int row = bm0 + w * 16 + r0 + r;
                    const int o = (head == 0) ? row * 40 + col
                                              : 409600 + row * 5 + col;
                    const float v = acc2[j][r] + bias;
                    if (isF32) ((float*)outv)[o] = v;
                    else ((__hip_bfloat16*)outv)[o] = __float2bfloat16(v);
                }
            }
        }
    }
}

// ---------------------------------------------------------------------------
// Kernel 3: bonds3 — grid 512 = (molecule, half). Each block: verified L1
// (P stored as fp16), then symmetric-fused pair phase in PACKED f16 using
// native _Float16 vectors (v_pk_add_f16 / v_pk_mul_f16 / v_pk_max_f16),
// one mfma_f32_16x16x32_f16 per unordered tile pair:
//   out[i][j] = out[j][i] = sum_k( lrelu(P1i+P2j) + lrelu(P1j+P2i) )*W + 2*bb2
// Halves split the 11 (m,jt) jobs per wave alternately. LDS 78.7 KB ->
// 2 blocks/CU, grid 512 = 2 blocks/CU resident (16 waves/CU).
// ---------------------------------------------------------------------------
__global__ __launch_bounds__(512) void bonds3_kernel(
    const void* __restrict__ Xv, const u16* __restrict__ WallT,
    const void* __restrict__ Wb2, const float* __restrict__ biasF,
    void* __restrict__ outv)
{
    __shared__ u16 Xm[48 * SK];    // bf16 (L1 input)
    __shared__ u16 P1L[48 * SK];   // fp16 bits
    __shared__ u16 P2L[48 * SK];   // fp16 bits
    __shared__ u16 WsB[5 * 264];   // fp16 bits (Wb2 transposed)
    __shared__ int fcnt;
    const int t = threadIdx.x;
    const int b = blockIdx.x >> 1;         // molecule
    const int h = blockIdx.x & 1;          // job half
    const int isF32 = computeIsF32((const u16*)Xv, &fcnt, t);

    if (isF32) {   // stage X rows 0..39 (fp32 -> bf16), zero rows 40..47
        const floatx4* __restrict__ src = (const floatx4*)((const float*)Xv + b * 10240);
        #pragma unroll
        for (int s = 0; s < 5; ++s) {
            int cid = t + s * 512;             // 2560 chunks of 4 floats
            int row = cid >> 6, ch = cid & 63;
            floatx4 f = src[cid];
            ushort4v u;
            u[0] = f2bf(f[0]); u[1] = f2bf(f[1]); u[2] = f2bf(f[2]); u[3] = f2bf(f[3]);
            *(ushort4v*)&Xm[row * SK + ch * 4] = u;
        }
        {   // zero rows 40..47
            int row = 40 + (t >> 6), ch = t & 63;
            ushort4v z = {0, 0, 0, 0};
            *(ushort4v*)&Xm[row * SK + ch * 4] = z;
        }
    } else {
        const int4v* __restrict__ src = (const int4v*)((const u16*)Xv + b * 10240);
        #pragma unroll
        for (int s = 0; s < 3; ++s) {
            int cid = t + s * 512;             // < 1536
            int row = cid >> 5, ch = cid & 31;
            if (cid < 1280) *(int4v*)&Xm[row * SK + ch * 8] = src[cid];
            else { int4v z = {0, 0, 0, 0}; *(int4v*)&Xm[row * SK + ch * 8] = z; }
        }
    }
    // Wb2[256][5] -> WsB[c][k] fp16, c<5
    #pragma unroll
    for (int s = 0; s < 3; ++s) {
        int e2 = t + s * 512;                  // < 1536
        if (e2 < 1280) {
            int c = e2 >> 8, k = e2 & 255;
            WsB[c * 264 + k] = ldWh(Wb2, k * 5 + c, isF32);
        }
    }
    __syncthreads();   // Xm + WsB visible

    const int w = t >> 6, l = t & 63;
    const int ml = l & 15, kq = l >> 4, r0 = kq * 4;

    // ---- layer 1 (verified frag pattern): P = X @ Wb1 (+bb1 on P1), fp16 out ----
    for (int n = 0; n < 4; ++n) {
        const int gc = (w + 8 * n) * 16 + ml;  // [0,512)
        floatx4 acc[3] = {};
        #pragma unroll
        for (int ks = 0; ks < 8; ++ks) {
            const int k0 = ks * 32 + kq * 8;
            bf16x8 bf = *(const bf16x8*)&WallT[(512 + gc) * 256 + k0];
            #pragma unroll
            for (int i = 0; i < 3; ++i) {
                bf16x8 a = *(const bf16x8*)&Xm[(i * 16 + ml) * SK + k0];
                acc[i] = __builtin_amdgcn_mfma_f32_16x16x32_bf16(a, bf, acc[i], 0, 0, 0);
            }
        }
        u16* dst = (gc < 256) ? P1L : P2L;
        const int col = gc & 255;
        const float bias = (gc < 256) ? biasF[512 + gc] : 0.f;   // bb1 on P1
        #pragma unroll
        for (int i = 0; i < 3; ++i)
            #pragma unroll
            for (int r = 0; r < 4; ++r)
                dst[(i * 16 + r0 + r) * SK + col] = f2h_bits(acc[i][r] + bias);
    }
    __syncthreads();

    // ---- symmetric-fused pair phase, packed f16 (native _Float16 vectors) ----
    const int sel = (ml < 5) ? ml : 4;         // ml>=5 feeds discarded D cols
    half8 wf[8];
    #pragma unroll
    for (int ks = 0; ks < 8; ++ks)
        wf[ks] = *(const half8*)&WsB[sel * 264 + ks * 32 + kq * 8];
    const float b2x2 = 2.f * biasF[816 + ml];  // ml>=5 reads zeros (in-bounds)
    const _Float16 c001 = (_Float16)0.01f;

    // 11 (m, jt) jobs per wave; halves take alternating jobs.
    constexpr int mT[11]  = {0, 0, 0, 1, 1, 1, 2, 2, 3, 3, 4};
    constexpr int jtT[11] = {0, 1, 2, 0, 1, 2, 1, 2, 1, 2, 2};
    #pragma unroll
    for (int idx = 0; idx < 11; ++idx) {
        if ((idx & 1) != h) continue;          // block-uniform
        const int m = mT[idx], jt = jtT[idx];
        const int i = w + 8 * m;               // [0,40)
        const bool diag = (jt == (i >> 4));    // wave-uniform per job
        floatx4 acc = {};
        #pragma unroll
        for (int ks = 0; ks < 8; ++ks) {
            const int k0 = ks * 32 + kq * 8;
            const uint4v a1 = *(const uint4v*)&P1L[i * SK + k0];              // P1[i]
            const uint4v a2 = *(const uint4v*)&P2L[i * SK + k0];              // P2[i]
            const uint4v b1 = *(const uint4v*)&P1L[(jt * 16 + ml) * SK + k0]; // P1[j]
            const uint4v b2 = *(const uint4v*)&P2L[(jt * 16 + ml) * SK + k0]; // P2[j]
            union { unsigned int u[4]; half8 v; } af;
            #pragma unroll
            for (int d = 0; d < 4; ++d) {
                const half2v tF = u2h2(a1[d]) + u2h2(b2[d]);   // v_pk_add_f16
                const half2v tB = u2h2(b1[d]) + u2h2(a2[d]);
                const half2v lF = __builtin_elementwise_max(tF, tF * c001);  // pk_max/pk_mul
                const half2v lB = __builtin_elementwise_max(tB, tB * c001);
                af.u[d] = h22u(lF + lB);
            }
            acc = __builtin_amdgcn_mfma_f32_16x16x32_f16(af.v, wf[ks], acc, 0, 0, 0);
        }
        if (ml < 5) {                          // D: row=kq*4+r -> j, col=ml -> class
            #pragma unroll
            for (int r = 0; r < 4; ++r) {
                const int j = jt * 16 + r0 + r;
                if (j < 40 && (!diag || j >= i)) {
                    const float v = acc[r] + b2x2;
                    const int o1 = 460800 + (b * 1600 + i * 40 + j) * 5 + ml;
                    if (isF32) ((float*)outv)[o1] = v;
                    else ((__hip_bfloat16*)outv)[o1] = __float2bfloat16(v);
                    if (!diag || j > i) {
                        const int o2 = 460800 + (b * 1600 + j * 40 + i) * 5 + ml;
                        if (isF32) ((float*)outv)[o2] = v;
                        else ((__hip_bfloat16*)outv)[o2] = __float2bfloat16(v);
                    }
                }
            }
        }
    }
}

// ---------------------------------------------------------------------------
extern "C" void kernel_launch(void* const* d_in, const int* in_sizes, int n_in,
                              void* d_out, int out_size, void* d_ws, size_t ws_size,
                              hipStream_t stream)
{
    const void* yhat = d_in[0];
    const void* Ws1  = d_in[1];
    const void* bs1  = d_in[2];
    const void* Ws2  = d_in[3];
    const void* bs2  = d_in[4];
    const void* Wc1  = d_in[5];
    const void* bc1  = d_in[6];
    const void* Wc2  = d_in[7];
    const void* bc2  = d_in[8];
    const void* Wb1  = d_in[9];
    const void* bb1  = d_in[10];
    const void* Wb2  = d_in[11];
    const void* bb2  = d_in[12];

    // workspace: 565248 bytes total (verified R0 layout)
    char* wsb = (char*)d_ws;
    float* biasF = (float*)(wsb + 4096);     // 1024 floats
    u16*   W2T   = (u16*)(wsb + 8192);       // 64*256 bf16  = 32768 B
    u16*   WallT = (u16*)(wsb + 40960);      // 1024*256 bf16 = 524288 B

    pack_kernel<<<132, 256, 0, stream>>>(yhat, Ws1, Wc1, Wb1, Ws2, Wc2,
                                         bs1, bc1, bb1, bs2, bc2, bb2,
                                         WallT, W2T, biasF);
    heads_kernel<<<dim3(160, 2), 256, 0, stream>>>(yhat, WallT, W2T, biasF, d_out);
    bonds3_kernel<<<512, 512, 0, stream>>>(yhat, WallT, Wb2, biasF, d_out);
}